// Round 11
// baseline (50.951 us; speedup 1.0000x reference)
//
#include <hip/hip_runtime.h>

// SplineConv: out[n, o, i] = sum_{a,b in 0..2} wx[n,a]*wy[n,b] * C[o,i,kx-2+a,ky-2+b]
// N=32768 points, C is (32,32,7,7) f32, out is (N,32,32) f32 = 128 MiB (HBM-write-bound).
//
// Round-11: two kernels.
//  PREP (one launch): blocks 0..127 compute per-point records (9 collapsed
//    weights + window offset, 48B each) into ws; blocks 128..131 transpose C
//    into CT[49][1024] so the main prologue is lane-contiguous.
//  MAIN: 512-thread blocks (all 1024 channels, 2 ch/thread), grid 512
//    (2 blocks/CU, 4 waves/SIMD). Prologue: 49 coalesced float2 loads from CT
//    (8 cache lines/load vs 64 for untransposed C - the round 5-10 hidden cost).
//    Loop: records read at UNIFORM addresses (scalar s_load path -> weights in
//    SGPRs), distance-2 prefetch in explicitly unrolled A/B bodies (no runtime
//    indexing -> no scratch). No LDS, no barriers in the loop. Per-point VALU
//    ~19 insts/wave = 152 cyc/SIMD < 188-cyc store floor -> store-bound.
// Window offset is READFIRSTLANE'd so the 25-way switch is a scalar jump table.

#define NPTS   32768
#define DIM    1024        // 32*32 channels
#define PPB    64          // points per main block
#define RSTR   12          // floats per record (48B, 16B-aligned)
#define NRECB  128         // prep blocks doing records (128*256 = 32768 points)

typedef float f32x2 __attribute__((ext_vector_type(2)));

__device__ __forceinline__ float safe_div(float n, float d) {
    return (d == 0.0f) ? n : (n / d);
}

__device__ __forceinline__ void span_weights(float v, const float* __restrict__ T,
                                             int& k, float& w0, float& w1, float& w2) {
    float t3 = T[3], t4 = T[4], t5 = T[5], t6 = T[6];
    k = 2 + (v >= t3) + (v >= t4) + (v >= t5) + (v >= t6);
    float Tm1 = T[k - 1], T0 = T[k], Tp1 = T[k + 1], Tp2 = T[k + 2];
    float a10 = safe_div(v - Tm1, Tp1 - Tm1);
    float a11 = safe_div(v - T0,  Tp2 - T0);
    float a21 = safe_div(v - T0,  Tp1 - T0);
    w0 = (1.0f - a21) * (1.0f - a10);
    w1 = (1.0f - a21) * a10 + a21 * (1.0f - a11);
    w2 = a21 * a11;
}

__global__ __launch_bounds__(256) void prep_kernel(
    const float* __restrict__ xy,
    const float* __restrict__ Tx,
    const float* __restrict__ Ty,
    const float* __restrict__ C,
    float* __restrict__ wts,
    float* __restrict__ CT)
{
    const int b = blockIdx.x;
    const int t = threadIdx.x;
    if (b < NRECB) {
        // --- per-point records ---
        const int n = b * 256 + t;
        const float2 pt = ((const float2*)xy)[n];
        int kx, ky;
        float wx0, wx1, wx2, wy0, wy1, wy2;
        span_weights(pt.x, Tx, kx, wx0, wx1, wx2);
        span_weights(pt.y, Ty, ky, wy0, wy1, wy2);
        float* r = wts + (size_t)n * RSTR;
        r[0] = wx0 * wy0;  r[1] = wx0 * wy1;  r[2] = wx0 * wy2;
        r[3] = wx1 * wy0;  r[4] = wx1 * wy1;  r[5] = wx1 * wy2;
        r[6] = wx2 * wy0;  r[7] = wx2 * wy1;  r[8] = wx2 * wy2;
        r[9] = __int_as_float((kx - 2) * 7 + (ky - 2));
        r[10] = 0.0f; r[11] = 0.0f;
    } else {
        // --- transpose C (32,32,7,7) -> CT[49][1024] ---
        const int ch = (b - NRECB) * 256 + t;
#pragma unroll
        for (int q = 0; q < 49; ++q)
            CT[q * DIM + ch] = C[(size_t)ch * 49 + q];
    }
}

__global__ __launch_bounds__(512, 4) void spline_main_kernel(
    const float* __restrict__ CT,
    const float* __restrict__ wts,
    float* __restrict__ out)
{
    const int t  = threadIdx.x;
    const int p0 = blockIdx.x * PPB;

    // Prologue: 2 channels (2t, 2t+1) x 49 coefficients from CT, coalesced
    // (lane-contiguous float2). PLANAR regs: c[q]=ch row, c[49+q]=ch+1 row.
    float c[98];
#pragma unroll
    for (int q = 0; q < 49; ++q) {
        f32x2 v = *(const f32x2*)(CT + q * DIM + 2 * t);
        c[q]      = v.x;
        c[49 + q] = v.y;
    }

    f32x2* outp = (f32x2*)(out + (size_t)p0 * DIM + 2 * t);
    const float* wp = wts + (size_t)p0 * RSTR;

    // Distance-2 record prefetch, explicit A/B register sets (rule #20:
    // no runtime indexing of the sets). Addresses are block-uniform ->
    // scalar-load path, weights live in SGPRs.
    float4 aA = *(const float4*)(wp + 0);
    float4 aB = *(const float4*)(wp + 4);
    float2 aC = *(const float2*)(wp + 8);
    float4 bA = *(const float4*)(wp + RSTR + 0);
    float4 bB = *(const float4*)(wp + RSTR + 4);
    float2 bC = *(const float2*)(wp + RSTR + 8);

#define BODY(WA, WB, WC, PF_IDX)                                        \
    {                                                                   \
        const int off = __builtin_amdgcn_readfirstlane(__float_as_int((WC).y)); \
        const float w0 = (WA).x, w1 = (WA).y, w2 = (WA).z, w3 = (WA).w; \
        const float w4 = (WB).x, w5 = (WB).y, w6 = (WB).z, w7 = (WB).w; \
        const float w8 = (WC).x;                                        \
        {   /* prefetch this set's next record (clamped, uniform) */    \
            const int j = (PF_IDX) < PPB ? (PF_IDX) : (PPB - 1);        \
            (WA) = *(const float4*)(wp + (size_t)j * RSTR + 0);         \
            (WB) = *(const float4*)(wp + (size_t)j * RSTR + 4);         \
            (WC) = *(const float2*)(wp + (size_t)j * RSTR + 8);         \
        }                                                               \
        float s0, s1;                                                   \
        switch (off) {                                                  \
        CASE_IJ(0, 0) CASE_IJ(0, 1) CASE_IJ(0, 2) CASE_IJ(0, 3) CASE_IJ(0, 4) \
        CASE_IJ(1, 0) CASE_IJ(1, 1) CASE_IJ(1, 2) CASE_IJ(1, 3) CASE_IJ(1, 4) \
        CASE_IJ(2, 0) CASE_IJ(2, 1) CASE_IJ(2, 2) CASE_IJ(2, 3) CASE_IJ(2, 4) \
        CASE_IJ(3, 0) CASE_IJ(3, 1) CASE_IJ(3, 2) CASE_IJ(3, 3) CASE_IJ(3, 4) \
        CASE_IJ(4, 0) CASE_IJ(4, 1) CASE_IJ(4, 2) CASE_IJ(4, 3) CASE_IJ(4, 4) \
        default: s0 = 0.0f; s1 = 0.0f; break;                           \
        }                                                               \
        f32x2 v2; v2.x = s0; v2.y = s1;                                 \
        __builtin_nontemporal_store(v2, outp);                          \
        outp += DIM / 2;                                                \
    }

#define TERM(q, dq, w)                                      \
            s0 = fmaf(w, c[(q) + (dq)],      s0);           \
            s1 = fmaf(w, c[49 + (q) + (dq)], s1);
#define CASE_IJ(i_, j_)                                     \
        case ((i_) * 7 + (j_)): {                           \
            const int q = (i_) * 7 + (j_);                  \
            s0 = w0 * c[q];                                 \
            s1 = w0 * c[49 + q];                            \
            TERM(q, 1,  w1)  TERM(q, 2,  w2)                \
            TERM(q, 7,  w3)  TERM(q, 8,  w4)  TERM(q, 9,  w5) \
            TERM(q, 14, w6)  TERM(q, 15, w7)  TERM(q, 16, w8) \
        } break;

    for (int i = 0; i < PPB; i += 2) {
        BODY(aA, aB, aC, i + 2)     // point i
        BODY(bA, bB, bC, i + 3)     // point i+1
    }

#undef CASE_IJ
#undef TERM
#undef BODY
}

extern "C" void kernel_launch(void* const* d_in, const int* in_sizes, int n_in,
                              void* d_out, int out_size, void* d_ws, size_t ws_size,
                              hipStream_t stream) {
    const float* xy = (const float*)d_in[0];
    const float* Tx = (const float*)d_in[1];
    const float* Ty = (const float*)d_in[2];
    const float* C  = (const float*)d_in[3];
    float* out = (float*)d_out;

    float* CT  = (float*)d_ws;                    // 49*1024 floats (200704 B, 16B-aligned)
    float* wts = CT + 49 * DIM;                   // 32768 x 12 floats

    prep_kernel<<<NRECB + DIM / 256, 256, 0, stream>>>(xy, Tx, Ty, C, wts, CT);
    spline_main_kernel<<<NPTS / PPB, 512, 0, stream>>>(CT, wts, out);
}

// Round 12
// 48.960 us; speedup vs baseline: 1.0407x; 1.0407x over previous
//
#include <hip/hip_runtime.h>

// SplineConv: out[n, o, i] = sum_{a,b in 0..2} wx[n,a]*wy[n,b] * C[o,i,kx-2+a,ky-2+b]
// N=32768 points, C is (32,32,7,7) f32, out is (N,32,32) f32 = 128 MiB (HBM-write-bound).
//
// Round-12 = round-5 (best: 38.4us) with ONE subsystem changed: the C prologue.
// Old prologue: 49 float2 loads at 392B lane stride -> 64 distinct cache lines
// per wave-load -> ~3136 L1 line-transactions/wave (~21us serialized front cost).
// New prologue: stage C via LDS in 8 chunks of 64 channels: coalesced float4
// global loads (16 lines/instr) -> LDS -> owner threads copy their two contiguous
// 98-float rows to registers (2-way bank alias = free). ~8x less line traffic.
// Loop unchanged from R5: fused LDS records, prefetch-1, readfirstlane scalar
// switch (vector switch if-converts to ~500 VALU ops/point), nt f32x2 stores.

#define NPTS   32768
#define DIM    1024        // 32*32 channels
#define PPB    64          // points per block
#define RSTR   12          // floats per LDS record (48B, 16B-aligned)
#define CHCH   64          // channels per prologue chunk
#define NCHK   8           // chunks (8*64 = 512 channels per block)

typedef float f32x2 __attribute__((ext_vector_type(2)));

__device__ __forceinline__ float safe_div(float n, float d) {
    return (d == 0.0f) ? n : (n / d);
}

__device__ __forceinline__ void span_weights(float v, const float* __restrict__ T,
                                             int& k, float& w0, float& w1, float& w2) {
    float t3 = T[3], t4 = T[4], t5 = T[5], t6 = T[6];
    k = 2 + (v >= t3) + (v >= t4) + (v >= t5) + (v >= t6);
    float Tm1 = T[k - 1], T0 = T[k], Tp1 = T[k + 1], Tp2 = T[k + 2];
    float a10 = safe_div(v - Tm1, Tp1 - Tm1);
    float a11 = safe_div(v - T0,  Tp2 - T0);
    float a21 = safe_div(v - T0,  Tp1 - T0);
    w0 = (1.0f - a21) * (1.0f - a10);
    w1 = (1.0f - a21) * a10 + a21 * (1.0f - a11);
    w2 = a21 * a11;
}

__global__ __launch_bounds__(256, 3) void spline_main_kernel(
    const float* __restrict__ C,
    const float* __restrict__ xy,
    const float* __restrict__ Tx,
    const float* __restrict__ Ty,
    float* __restrict__ out)
{
    __shared__ float recs[PPB][RSTR];          // 3 KB
    __shared__ float cbuf[CHCH * 49];          // 12.25 KB staging chunk

    const int t     = threadIdx.x;
    const int g     = blockIdx.x & 1;          // channel half: 0 or 1
    const int chunk = blockIdx.x >> 1;
    const int p0    = chunk * PPB;
    const int ch    = g * 512 + t * 2;         // this thread's first channel

    // --- Threads 0-63: compute this block's 64 point-records into LDS -------
    if (t < PPB) {
        const int p = p0 + t;
        const float2 pt = ((const float2*)xy)[p];
        int kx, ky;
        float wx0, wx1, wx2, wy0, wy1, wy2;
        span_weights(pt.x, Tx, kx, wx0, wx1, wx2);
        span_weights(pt.y, Ty, ky, wy0, wy1, wy2);
        float* r = recs[t];
        r[0] = wx0 * wy0;  r[1] = wx0 * wy1;  r[2] = wx0 * wy2;
        r[3] = wx1 * wy0;  r[4] = wx1 * wy1;  r[5] = wx1 * wy2;
        r[6] = wx2 * wy0;  r[7] = wx2 * wy1;  r[8] = wx2 * wy2;
        r[9] = __int_as_float((kx - 2) * 7 + (ky - 2));
        r[10] = 0.0f; r[11] = 0.0f;
    }

    // --- Prologue: C -> LDS (coalesced) -> registers, 8 chunks of 64 channels.
    // c[0..48] = row ch, c[49..97] = row ch+1 (planar, compile-time indices).
    float c[98];
#pragma unroll
    for (int k = 0; k < NCHK; ++k) {
        // Stage channels [g*512 + k*64, +64): 3136 floats = 784 float4, coalesced.
        const float4* src = (const float4*)(C + ((size_t)g * 512 + k * CHCH) * 49);
        for (int i = t; i < (CHCH * 49) / 4; i += 256)
            ((float4*)cbuf)[i] = src[i];
        __syncthreads();
        if ((t >> 5) == k) {
            // Owner threads t in [32k, 32k+32): channels 2t,2t+1 are rows
            // (2t - 64k) and +1 -> contiguous 98 floats at cbuf + (t&31)*98.
            const float* row = cbuf + (t & 31) * 98;
#pragma unroll
            for (int q = 0; q < 98; ++q) c[q] = row[q];
        }
        __syncthreads();
    }

    f32x2* outp = (f32x2*)(out + (size_t)p0 * DIM + ch);

    // Prefetch first record (uniform LDS address -> broadcast). R5 loop verbatim.
    float4 wAn = *(const float4*)(&recs[0][0]);
    float4 wBn = *(const float4*)(&recs[0][4]);
    float2 wCn = *(const float2*)(&recs[0][8]);

    for (int i = 0; i < PPB; ++i) {
        const float w0 = wAn.x, w1 = wAn.y, w2 = wAn.z, w3 = wAn.w;
        const float w4 = wBn.x, w5 = wBn.y, w6 = wBn.z, w7 = wBn.w;
        const float w8 = wCn.x;
        const int off = __builtin_amdgcn_readfirstlane(__float_as_int(wCn.y));

        if (i + 1 < PPB) {   // prefetch next record under this point's FMAs
            wAn = *(const float4*)(&recs[i + 1][0]);
            wBn = *(const float4*)(&recs[i + 1][4]);
            wCn = *(const float2*)(&recs[i + 1][8]);
        }

        float s0, s1;
        switch (off) {
#define TERM(q, dq, w)                                      \
            s0 = fmaf(w, c[(q) + (dq)],      s0);           \
            s1 = fmaf(w, c[49 + (q) + (dq)], s1);
#define CASE_IJ(i_, j_)                                     \
        case ((i_) * 7 + (j_)): {                           \
            const int q = (i_) * 7 + (j_);                  \
            s0 = w0 * c[q];                                 \
            s1 = w0 * c[49 + q];                            \
            TERM(q, 1,  w1)  TERM(q, 2,  w2)                \
            TERM(q, 7,  w3)  TERM(q, 8,  w4)  TERM(q, 9,  w5) \
            TERM(q, 14, w6)  TERM(q, 15, w7)  TERM(q, 16, w8) \
        } break;
        CASE_IJ(0, 0) CASE_IJ(0, 1) CASE_IJ(0, 2) CASE_IJ(0, 3) CASE_IJ(0, 4)
        CASE_IJ(1, 0) CASE_IJ(1, 1) CASE_IJ(1, 2) CASE_IJ(1, 3) CASE_IJ(1, 4)
        CASE_IJ(2, 0) CASE_IJ(2, 1) CASE_IJ(2, 2) CASE_IJ(2, 3) CASE_IJ(2, 4)
        CASE_IJ(3, 0) CASE_IJ(3, 1) CASE_IJ(3, 2) CASE_IJ(3, 3) CASE_IJ(3, 4)
        CASE_IJ(4, 0) CASE_IJ(4, 1) CASE_IJ(4, 2) CASE_IJ(4, 3) CASE_IJ(4, 4)
#undef CASE_IJ
#undef TERM
        default: s0 = 0.0f; s1 = 0.0f; break;
        }

        // Streaming 8B/lane coalesced nontemporal store.
        f32x2 v2; v2.x = s0; v2.y = s1;
        __builtin_nontemporal_store(v2, outp);
        outp += DIM / 2;
    }
}

extern "C" void kernel_launch(void* const* d_in, const int* in_sizes, int n_in,
                              void* d_out, int out_size, void* d_ws, size_t ws_size,
                              hipStream_t stream) {
    const float* xy = (const float*)d_in[0];
    const float* Tx = (const float*)d_in[1];
    const float* Ty = (const float*)d_in[2];
    const float* C  = (const float*)d_in[3];
    float* out = (float*)d_out;

    spline_main_kernel<<<2 * (NPTS / PPB), 256, 0, stream>>>(C, xy, Tx, Ty, out);
}

// Round 13
// 48.939 us; speedup vs baseline: 1.0411x; 1.0004x over previous
//
#include <hip/hip_runtime.h>

// SplineConv as skinny-K GEMM: out[n,oi] = sum_k W[n,k] * CT[k,oi],
// W = dense-64-padded spline weight rows (9 nonzeros), CT = C transposed.
// M=32768, N=1024, K=64. f16 MFMA (16x16x32, f32 acc): partition-of-unity
// weights + |C|<=0.5 => f16 error ~5e-4 << 5.4e-3 threshold.
//
// prep_kernel: writes W_perm (4 MiB) and B_perm (128 KiB) in EXACT MFMA
//   fragment order (A: row=lane%16, k=(lane/16)*8+j; B: col=lane%16, same k),
//   so all main-kernel loads are coalesced 16B/lane dwordx4.
// main_kernel: 256 thr = 4 waves; block = 64 points x 512 channels (wave: 128
//   channels = 8 n-tiles, B-frags register-resident). 64 MFMAs/wave; D layout
//   row=(lane>>4)*4+reg, col=lane&15 (guide m89). Nontemporal dword stores.
// Store floor ~20us; everything else hides under the store stream.

#define NPTS   32768
#define DIM    1024
#define MT     (NPTS / 16)        // 2048 m-tiles
#define NT     (DIM / 16)         // 64 n-tiles
#define WELEM  (MT * 2 * 64 * 8)  // W_perm f16 elements (4 MiB)

typedef _Float16 f16x8 __attribute__((ext_vector_type(8)));
typedef float    f32x4 __attribute__((ext_vector_type(4)));

__device__ __forceinline__ float safe_div(float n, float d) {
    return (d == 0.0f) ? n : (n / d);
}

__device__ __forceinline__ void span_weights(float v, const float* __restrict__ T,
                                             int& k, float& w0, float& w1, float& w2) {
    float t3 = T[3], t4 = T[4], t5 = T[5], t6 = T[6];
    k = 2 + (v >= t3) + (v >= t4) + (v >= t5) + (v >= t6);
    float Tm1 = T[k - 1], T0 = T[k], Tp1 = T[k + 1], Tp2 = T[k + 2];
    float a10 = safe_div(v - Tm1, Tp1 - Tm1);
    float a11 = safe_div(v - T0,  Tp2 - T0);
    float a21 = safe_div(v - T0,  Tp1 - T0);
    w0 = (1.0f - a21) * (1.0f - a10);
    w1 = (1.0f - a21) * a10 + a21 * (1.0f - a11);
    w2 = a21 * a11;
}

__global__ __launch_bounds__(256) void prep_kernel(
    const float* __restrict__ xy,
    const float* __restrict__ Tx,
    const float* __restrict__ Ty,
    const float* __restrict__ C,
    _Float16* __restrict__ Wp,
    _Float16* __restrict__ Bp)
{
    const int b = blockIdx.x;
    const int t = threadIdx.x;
    if (b < MT / 2) {
        // ---- W_perm: one thread per (m-tile, k-step, lane) 16B record ----
        const int id   = b * 256 + t;          // 0 .. 262143
        const int lane = id & 63;
        const int step = (id >> 6) & 1;
        const int tile = id >> 7;
        const int n    = tile * 16 + (lane & 15);   // A row = lane%16
        const int g    = lane >> 4;                  // k-group

        const float2 pt = ((const float2*)xy)[n];
        int kx, ky;
        float wx0, wx1, wx2, wy0, wy1, wy2;
        span_weights(pt.x, Tx, kx, wx0, wx1, wx2);
        span_weights(pt.y, Ty, ky, wy0, wy1, wy2);
        const int off = (kx - 2) * 7 + (ky - 2);

        f16x8 frag;
#pragma unroll
        for (int j = 0; j < 8; ++j) {
            const int k   = step * 32 + g * 8 + j;
            const int rel = k - off;
            const float va = (rel >= 14) ? wx2 : ((rel >= 7) ? wx1 : wx0);
            const int   bb = rel - ((rel >= 14) ? 14 : ((rel >= 7) ? 7 : 0));
            const float vb = (bb == 0) ? wy0 : ((bb == 1) ? wy1 : wy2);
            const bool valid = (rel >= 0) && (rel <= 16) && (bb >= 0) && (bb <= 2);
            frag[j] = (_Float16)(valid ? va * vb : 0.0f);
        }
        *(f16x8*)(Wp + (size_t)id * 8) = frag;
    } else if (b < MT / 2 + 32) {
        // ---- B_perm: CT[k][ch] in B-fragment order ----
        const int id    = (b - MT / 2) * 256 + t;   // 0 .. 8191
        const int lane  = id & 63;
        const int step  = (id >> 6) & 1;
        const int ntile = id >> 7;
        const int ch    = ntile * 16 + (lane & 15); // B col = lane%16
        const int g     = lane >> 4;

        f16x8 frag;
#pragma unroll
        for (int j = 0; j < 8; ++j) {
            const int k = step * 32 + g * 8 + j;
            frag[j] = (_Float16)((k < 49) ? C[(size_t)ch * 49 + k] : 0.0f);
        }
        *(f16x8*)(Bp + (size_t)id * 8) = frag;
    }
}

__global__ __launch_bounds__(256, 4) void spline_mfma_kernel(
    const _Float16* __restrict__ Wp,
    const _Float16* __restrict__ Bp,
    float* __restrict__ out)
{
    const int t      = threadIdx.x;
    const int lane   = t & 63;
    const int w      = t >> 6;                 // wave 0..3
    const int mchunk = blockIdx.x >> 1;        // 64-point chunk
    const int nhalf  = blockIdx.x & 1;         // 512-channel half

    // B-fragments for this wave's 8 n-tiles x 2 k-steps (register-resident).
    f16x8 bf[8][2];
#pragma unroll
    for (int nt = 0; nt < 8; ++nt)
#pragma unroll
        for (int st = 0; st < 2; ++st) {
            const int ntg = nhalf * 32 + w * 8 + nt;
            bf[nt][st] = *(const f16x8*)(Bp + ((size_t)(ntg * 2 + st) * 64 + lane) * 8);
        }

    const int colbase = nhalf * 512 + w * 128 + (lane & 15);

#pragma unroll
    for (int mt = 0; mt < 4; ++mt) {
        const int tile = mchunk * 4 + mt;
        const f16x8 a0 = *(const f16x8*)(Wp + ((size_t)(tile * 2 + 0) * 64 + lane) * 8);
        const f16x8 a1 = *(const f16x8*)(Wp + ((size_t)(tile * 2 + 1) * 64 + lane) * 8);

        f32x4 acc[8];
#pragma unroll
        for (int nt = 0; nt < 8; ++nt) {
            f32x4 z; z[0] = 0.0f; z[1] = 0.0f; z[2] = 0.0f; z[3] = 0.0f;
            acc[nt] = __builtin_amdgcn_mfma_f32_16x16x32_f16(a0, bf[nt][0], z, 0, 0, 0);
        }
#pragma unroll
        for (int nt = 0; nt < 8; ++nt)
            acc[nt] = __builtin_amdgcn_mfma_f32_16x16x32_f16(a1, bf[nt][1], acc[nt], 0, 0, 0);

        const int rowbase = mchunk * 64 + mt * 16 + (lane >> 4) * 4;
#pragma unroll
        for (int nt = 0; nt < 8; ++nt)
#pragma unroll
            for (int r = 0; r < 4; ++r) {
                float* dst = out + (size_t)(rowbase + r) * DIM + colbase + nt * 16;
                __builtin_nontemporal_store(acc[nt][r], dst);
            }
    }
}

extern "C" void kernel_launch(void* const* d_in, const int* in_sizes, int n_in,
                              void* d_out, int out_size, void* d_ws, size_t ws_size,
                              hipStream_t stream) {
    const float* xy = (const float*)d_in[0];
    const float* Tx = (const float*)d_in[1];
    const float* Ty = (const float*)d_in[2];
    const float* C  = (const float*)d_in[3];
    float* out = (float*)d_out;

    _Float16* Wp = (_Float16*)d_ws;            // 4 MiB
    _Float16* Bp = Wp + WELEM;                 // 128 KiB

    prep_kernel<<<MT / 2 + 32, 256, 0, stream>>>(xy, Tx, Ty, C, Wp, Bp);
    spline_mfma_kernel<<<2 * (NPTS / 64), 256, 0, stream>>>(Wp, Bp, out);
}

// Round 14
// 41.546 us; speedup vs baseline: 1.2264x; 1.1779x over previous
//
#include <hip/hip_runtime.h>

// SplineConv as skinny-K GEMM: out[n,oi] = sum_k W[n,k] * CT[k,oi],
// W = dense-64-padded spline weight rows (9 nonzeros), CT = C transposed.
// M=32768 points, N=1024 channels, K=64. f16 MFMA 16x16x32, f32 acc
// (partition-of-unity weights + |C|<=0.5 -> f16 error ~5e-4 << 5.4e-3 thr).
//
// Round-14 = round-13 (correct, 48.9us) with OPERANDS SWAPPED so channels are
// D-rows and points are D-cols. A/B fragment packings are identical
// (row/col = lane%16, k = (lane>>4)*8+j), so prep_kernel is unchanged
// (verified by R13's pass). D layout (m89): row=(lane>>4)*4+reg, col=lane&15
// -> each lane's 4 acc regs = 4 CONSECUTIVE CHANNELS of one point
// -> one contiguous f32x4 store per acc (1KB/wave-instr, like the 6.7TB/s
// fill kernel) instead of R13's 128 scalar 4B stores fanning 4 rows/instr.
// Plain (non-nt) stores so L2 combines 64B segments into full 128B lines.

#define NPTS   32768
#define DIM    1024
#define MT     (NPTS / 16)        // 2048 point-tiles
#define WELEM  (MT * 2 * 64 * 8)  // W_perm f16 elements (4 MiB)

typedef _Float16 f16x8 __attribute__((ext_vector_type(8)));
typedef float    f32x4 __attribute__((ext_vector_type(4)));

__device__ __forceinline__ float safe_div(float n, float d) {
    return (d == 0.0f) ? n : (n / d);
}

__device__ __forceinline__ void span_weights(float v, const float* __restrict__ T,
                                             int& k, float& w0, float& w1, float& w2) {
    float t3 = T[3], t4 = T[4], t5 = T[5], t6 = T[6];
    k = 2 + (v >= t3) + (v >= t4) + (v >= t5) + (v >= t6);
    float Tm1 = T[k - 1], T0 = T[k], Tp1 = T[k + 1], Tp2 = T[k + 2];
    float a10 = safe_div(v - Tm1, Tp1 - Tm1);
    float a11 = safe_div(v - T0,  Tp2 - T0);
    float a21 = safe_div(v - T0,  Tp1 - T0);
    w0 = (1.0f - a21) * (1.0f - a10);
    w1 = (1.0f - a21) * a10 + a21 * (1.0f - a11);
    w2 = a21 * a11;
}

__global__ __launch_bounds__(256) void prep_kernel(
    const float* __restrict__ xy,
    const float* __restrict__ Tx,
    const float* __restrict__ Ty,
    const float* __restrict__ C,
    _Float16* __restrict__ Wp,
    _Float16* __restrict__ Cp)
{
    const int b = blockIdx.x;
    const int t = threadIdx.x;
    if (b < MT / 2) {
        // ---- W_perm: one thread per (point-tile, k-step, lane) 16B record ----
        const int id   = b * 256 + t;          // 0 .. 262143
        const int lane = id & 63;
        const int step = (id >> 6) & 1;
        const int tile = id >> 7;
        const int n    = tile * 16 + (lane & 15);   // B col = lane%16
        const int g    = lane >> 4;                  // k-group

        const float2 pt = ((const float2*)xy)[n];
        int kx, ky;
        float wx0, wx1, wx2, wy0, wy1, wy2;
        span_weights(pt.x, Tx, kx, wx0, wx1, wx2);
        span_weights(pt.y, Ty, ky, wy0, wy1, wy2);
        const int off = (kx - 2) * 7 + (ky - 2);

        f16x8 frag;
#pragma unroll
        for (int j = 0; j < 8; ++j) {
            const int k   = step * 32 + g * 8 + j;
            const int rel = k - off;
            const float va = (rel >= 14) ? wx2 : ((rel >= 7) ? wx1 : wx0);
            const int   bb = rel - ((rel >= 14) ? 14 : ((rel >= 7) ? 7 : 0));
            const float vb = (bb == 0) ? wy0 : ((bb == 1) ? wy1 : wy2);
            const bool valid = (rel >= 0) && (rel <= 16) && (bb >= 0) && (bb <= 2);
            frag[j] = (_Float16)(valid ? va * vb : 0.0f);
        }
        *(f16x8*)(Wp + (size_t)id * 8) = frag;
    } else if (b < MT / 2 + 32) {
        // ---- C_perm: C[ch][k] in A-fragment order (row=ch, k-grouped) ----
        const int id    = (b - MT / 2) * 256 + t;   // 0 .. 8191
        const int lane  = id & 63;
        const int step  = (id >> 6) & 1;
        const int ctile = id >> 7;
        const int ch    = ctile * 16 + (lane & 15); // A row = lane%16
        const int g     = lane >> 4;

        f16x8 frag;
#pragma unroll
        for (int j = 0; j < 8; ++j) {
            const int k = step * 32 + g * 8 + j;
            frag[j] = (_Float16)((k < 49) ? C[(size_t)ch * 49 + k] : 0.0f);
        }
        *(f16x8*)(Cp + (size_t)id * 8) = frag;
    }
}

__global__ __launch_bounds__(256, 4) void spline_mfma_kernel(
    const _Float16* __restrict__ Wp,
    const _Float16* __restrict__ Cp,
    float* __restrict__ out)
{
    const int t      = threadIdx.x;
    const int lane   = t & 63;
    const int w      = t >> 6;                 // wave 0..3
    const int chgrp  = blockIdx.x & 3;         // 256-channel group
    const int pchunk = blockIdx.x >> 2;        // 8 point-tile chunk (128 points)

    // A-fragments: this wave's 4 channel-tiles x 2 k-steps (register-resident,
    // Cp is 128 KiB -> L2-hot for every block).
    f16x8 af[4][2];
#pragma unroll
    for (int ct = 0; ct < 4; ++ct)
#pragma unroll
        for (int st = 0; st < 2; ++st) {
            const int ctg = chgrp * 16 + w * 4 + ct;
            af[ct][st] = *(const f16x8*)(Cp + ((size_t)(ctg * 2 + st) * 64 + lane) * 8);
        }

    // D row = channel = (lane>>4)*4 + reg  -> 4 consecutive channels per lane.
    const int chbase = chgrp * 256 + w * 64 + (lane >> 4) * 4;

#pragma unroll
    for (int pt = 0; pt < 8; ++pt) {
        const int ptile = pchunk * 8 + pt;
        const f16x8 b0 = *(const f16x8*)(Wp + ((size_t)(ptile * 2 + 0) * 64 + lane) * 8);
        const f16x8 b1 = *(const f16x8*)(Wp + ((size_t)(ptile * 2 + 1) * 64 + lane) * 8);

        f32x4 acc[4];
#pragma unroll
        for (int ct = 0; ct < 4; ++ct) {
            f32x4 z; z[0] = 0.0f; z[1] = 0.0f; z[2] = 0.0f; z[3] = 0.0f;
            acc[ct] = __builtin_amdgcn_mfma_f32_16x16x32_f16(af[ct][0], b0, z, 0, 0, 0);
        }
#pragma unroll
        for (int ct = 0; ct < 4; ++ct)
            acc[ct] = __builtin_amdgcn_mfma_f32_16x16x32_f16(af[ct][1], b1, acc[ct], 0, 0, 0);

        // D col = point = lane&15. One contiguous 16B store per acc.
        float* prow = out + (size_t)(ptile * 16 + (lane & 15)) * DIM + chbase;
#pragma unroll
        for (int ct = 0; ct < 4; ++ct)
            *(f32x4*)(prow + ct * 16) = acc[ct];
    }
}

extern "C" void kernel_launch(void* const* d_in, const int* in_sizes, int n_in,
                              void* d_out, int out_size, void* d_ws, size_t ws_size,
                              hipStream_t stream) {
    const float* xy = (const float*)d_in[0];
    const float* Tx = (const float*)d_in[1];
    const float* Ty = (const float*)d_in[2];
    const float* C  = (const float*)d_in[3];
    float* out = (float*)d_out;

    _Float16* Wp = (_Float16*)d_ws;            // 4 MiB
    _Float16* Cp = Wp + WELEM;                 // 128 KiB

    prep_kernel<<<MT / 2 + 32, 256, 0, stream>>>(xy, Tx, Ty, C, Wp, Cp);
    spline_mfma_kernel<<<4 * (MT / 8), 256, 0, stream>>>(Wp, Cp, out);
}

// Round 15
// 36.892 us; speedup vs baseline: 1.3811x; 1.1262x over previous
//
#include <hip/hip_runtime.h>

// SplineConv as skinny-K GEMM: out[n,oi] = sum_k W[n,k] * CT[k,oi].
// M=32768 points, N=1024 channels, K=64. f16 MFMA 16x16x32, f32 acc.
//
// Round-15 = round-14 (41.5us, correct) with ONE change: stores go through an
// LDS transpose so each global store instruction is 64 lanes x 16B contiguous
// = 1KiB full-line (the 6.7TB/s fill kernel's pattern), instead of R14's 16
// scattered 64B half-line segments per instruction.
//  - Per pt-tile iter: block holds 16 points x 256 ch (16KiB). ds_write acc
//    with XOR swizzle (ci ^ ((p&7)<<2), 16B granularity): 8 lanes/bank-quad
//    both directions = LDS minimum, conflict-free. 1 barrier/iter via double
//    buffer (32KiB). Each wave then stores 4 complete 1KiB point-rows.
//  - Compute + prep identical to R14 (verified: absmax 1.95e-3).

#define NPTS   32768
#define DIM    1024
#define MT     (NPTS / 16)        // 2048 point-tiles
#define WELEM  (MT * 2 * 64 * 8)  // W_perm f16 elements (4 MiB)

typedef _Float16 f16x8 __attribute__((ext_vector_type(8)));
typedef float    f32x4 __attribute__((ext_vector_type(4)));

__device__ __forceinline__ float safe_div(float n, float d) {
    return (d == 0.0f) ? n : (n / d);
}

__device__ __forceinline__ void span_weights(float v, const float* __restrict__ T,
                                             int& k, float& w0, float& w1, float& w2) {
    float t3 = T[3], t4 = T[4], t5 = T[5], t6 = T[6];
    k = 2 + (v >= t3) + (v >= t4) + (v >= t5) + (v >= t6);
    float Tm1 = T[k - 1], T0 = T[k], Tp1 = T[k + 1], Tp2 = T[k + 2];
    float a10 = safe_div(v - Tm1, Tp1 - Tm1);
    float a11 = safe_div(v - T0,  Tp2 - T0);
    float a21 = safe_div(v - T0,  Tp1 - T0);
    w0 = (1.0f - a21) * (1.0f - a10);
    w1 = (1.0f - a21) * a10 + a21 * (1.0f - a11);
    w2 = a21 * a11;
}

__global__ __launch_bounds__(256) void prep_kernel(
    const float* __restrict__ xy,
    const float* __restrict__ Tx,
    const float* __restrict__ Ty,
    const float* __restrict__ C,
    _Float16* __restrict__ Wp,
    _Float16* __restrict__ Cp)
{
    const int b = blockIdx.x;
    const int t = threadIdx.x;
    if (b < MT / 2) {
        // ---- W_perm: one thread per (point-tile, k-step, lane) 16B record ----
        const int id   = b * 256 + t;          // 0 .. 262143
        const int lane = id & 63;
        const int step = (id >> 6) & 1;
        const int tile = id >> 7;
        const int n    = tile * 16 + (lane & 15);   // B col = lane%16
        const int g    = lane >> 4;                  // k-group

        const float2 pt = ((const float2*)xy)[n];
        int kx, ky;
        float wx0, wx1, wx2, wy0, wy1, wy2;
        span_weights(pt.x, Tx, kx, wx0, wx1, wx2);
        span_weights(pt.y, Ty, ky, wy0, wy1, wy2);
        const int off = (kx - 2) * 7 + (ky - 2);

        f16x8 frag;
#pragma unroll
        for (int j = 0; j < 8; ++j) {
            const int k   = step * 32 + g * 8 + j;
            const int rel = k - off;
            const float va = (rel >= 14) ? wx2 : ((rel >= 7) ? wx1 : wx0);
            const int   bb = rel - ((rel >= 14) ? 14 : ((rel >= 7) ? 7 : 0));
            const float vb = (bb == 0) ? wy0 : ((bb == 1) ? wy1 : wy2);
            const bool valid = (rel >= 0) && (rel <= 16) && (bb >= 0) && (bb <= 2);
            frag[j] = (_Float16)(valid ? va * vb : 0.0f);
        }
        *(f16x8*)(Wp + (size_t)id * 8) = frag;
    } else if (b < MT / 2 + 32) {
        // ---- C_perm: C[ch][k] in A-fragment order (row=ch, k-grouped) ----
        const int id    = (b - MT / 2) * 256 + t;   // 0 .. 8191
        const int lane  = id & 63;
        const int step  = (id >> 6) & 1;
        const int ctile = id >> 7;
        const int ch    = ctile * 16 + (lane & 15); // A row = lane%16
        const int g     = lane >> 4;

        f16x8 frag;
#pragma unroll
        for (int j = 0; j < 8; ++j) {
            const int k = step * 32 + g * 8 + j;
            frag[j] = (_Float16)((k < 49) ? C[(size_t)ch * 49 + k] : 0.0f);
        }
        *(f16x8*)(Cp + (size_t)id * 8) = frag;
    }
}

__global__ __launch_bounds__(256, 4) void spline_mfma_kernel(
    const _Float16* __restrict__ Wp,
    const _Float16* __restrict__ Cp,
    float* __restrict__ out)
{
    __shared__ float lds[2][16 * 256];         // 32 KiB double buffer

    const int t      = threadIdx.x;
    const int lane   = t & 63;
    const int w      = t >> 6;                 // wave 0..3
    const int chgrp  = blockIdx.x & 3;         // 256-channel group
    const int pchunk = blockIdx.x >> 2;        // 8 point-tile chunk (128 points)

    // A-fragments: this wave's 4 channel-tiles x 2 k-steps (register-resident;
    // Cp is 128 KiB -> L2-hot for every block).
    f16x8 af[4][2];
#pragma unroll
    for (int ct = 0; ct < 4; ++ct)
#pragma unroll
        for (int st = 0; st < 2; ++st) {
            const int ctg = chgrp * 16 + w * 4 + ct;
            af[ct][st] = *(const f16x8*)(Cp + ((size_t)(ctg * 2 + st) * 64 + lane) * 8);
        }

    const int p = lane & 15;                   // D col = point within tile
    const int h = lane >> 4;                   // D row group

#pragma unroll
    for (int pt = 0; pt < 8; ++pt) {
        const int ptile = pchunk * 8 + pt;
        const f16x8 b0 = *(const f16x8*)(Wp + ((size_t)(ptile * 2 + 0) * 64 + lane) * 8);
        const f16x8 b1 = *(const f16x8*)(Wp + ((size_t)(ptile * 2 + 1) * 64 + lane) * 8);

        f32x4 acc[4];
#pragma unroll
        for (int ct = 0; ct < 4; ++ct) {
            f32x4 z; z[0] = 0.0f; z[1] = 0.0f; z[2] = 0.0f; z[3] = 0.0f;
            acc[ct] = __builtin_amdgcn_mfma_f32_16x16x32_f16(af[ct][0], b0, z, 0, 0, 0);
        }
#pragma unroll
        for (int ct = 0; ct < 4; ++ct)
            acc[ct] = __builtin_amdgcn_mfma_f32_16x16x32_f16(af[ct][1], b1, acc[ct], 0, 0, 0);

        // --- LDS transpose: acc[ct] = channels (w*64 + ct*16 + h*4 .. +4) of
        // point p, within this block's 256-channel slice. XOR-swizzled. ---
        float* buf = lds[pt & 1];
#pragma unroll
        for (int ct = 0; ct < 4; ++ct) {
            const int ci = w * 64 + ct * 16 + h * 4;
            *(f32x4*)(buf + p * 256 + (ci ^ ((p & 7) << 2))) = acc[ct];
        }
        __syncthreads();

        // --- Cooperative store: wave w emits points 4w..4w+3, each as one
        // 64-lane x 16B contiguous 1KiB full-line nontemporal store. ---
#pragma unroll
        for (int r = 0; r < 4; ++r) {
            const int pr = 4 * w + r;
            const int ci = lane * 4;
            f32x4 v = *(const f32x4*)(buf + pr * 256 + (ci ^ ((pr & 7) << 2)));
            float* dst = out + (size_t)(ptile * 16 + pr) * DIM + chgrp * 256 + ci;
            __builtin_nontemporal_store(v, (f32x4*)dst);
        }
        // Double buffer: next iter writes lds[(pt+1)&1]; slowest wave can still
        // be reading lds[pt&1] -> no second barrier needed.
    }
}

extern "C" void kernel_launch(void* const* d_in, const int* in_sizes, int n_in,
                              void* d_out, int out_size, void* d_ws, size_t ws_size,
                              hipStream_t stream) {
    const float* xy = (const float*)d_in[0];
    const float* Tx = (const float*)d_in[1];
    const float* Ty = (const float*)d_in[2];
    const float* C  = (const float*)d_in[3];
    float* out = (float*)d_out;

    _Float16* Wp = (_Float16*)d_ws;            // 4 MiB
    _Float16* Cp = Wp + WELEM;                 // 128 KiB

    prep_kernel<<<MT / 2 + 32, 256, 0, stream>>>(xy, Tx, Ty, C, Wp, Cp);
    spline_mfma_kernel<<<4 * (MT / 8), 256, 0, stream>>>(Wp, Cp, out);
}